// Round 17
// baseline (185.097 us; speedup 1.0000x reference)
//
#include <hip/hip_runtime.h>
#include <hip/hip_bf16.h>
#include <math.h>

constexpr int DM = 1024;    // d_model
constexpr int NH = 16;      // heads
constexpr int DK = 64;      // head dim
constexpr int SQ = 2048;    // seq len
constexpr int BB = 2;       // batch
constexpr int MR = BB * SQ; // 4096 rows

typedef short bf16x8 __attribute__((ext_vector_type(8)));
typedef float f32x4 __attribute__((ext_vector_type(4)));
typedef float f32x16 __attribute__((ext_vector_type(16)));

__device__ inline unsigned short f2bf(float f) {
  unsigned u = __float_as_uint(f);
  unsigned r = (u + 0x7fffu + ((u >> 16) & 1u)) >> 16;  // RNE
  return (unsigned short)r;
}

// XOR swizzle for [R][64] bf16 LDS tiles. f(r) xors the 16B-granule index.
__device__ inline int fswz(int r) { return (r & 7) ^ ((r >> 3) & 7); }
__device__ inline int swz(int r, int c) {
  return r * 64 + ((((c >> 3) ^ fswz(r)) & 7) << 3) + (c & 7);
}

// -------- cast f32 -> bf16, 8 elems/thread --------
__global__ __launch_bounds__(256)
void cast_kernel(const float* __restrict__ in, unsigned short* __restrict__ out, int n8) {
  int i = blockIdx.x * 256 + threadIdx.x;
  if (i >= n8) return;
  float4 a = *(const float4*)&in[(size_t)i * 8];
  float4 b = *(const float4*)&in[(size_t)i * 8 + 4];
  ushort4 lo = {f2bf(a.x), f2bf(a.y), f2bf(a.z), f2bf(a.w)};
  ushort4 hi = {f2bf(b.x), f2bf(b.y), f2bf(b.z), f2bf(b.w)};
  *(ushort4*)&out[(size_t)i * 8] = lo;
  *(ushort4*)&out[(size_t)i * 8 + 4] = hi;
}

// -------- cast+transpose all 4 weights: z picks {Wq,Wk,Wv,Wo} --------
__global__ __launch_bounds__(256)
void transpose_cast_all(const float* __restrict__ Wq, const float* __restrict__ Wk,
                        const float* __restrict__ Wv, const float* __restrict__ Wo,
                        unsigned short* __restrict__ Wt3, unsigned short* __restrict__ Wto) {
  __shared__ float tl[32][33];
  const int z = blockIdx.z;
  const float* W = (z == 0) ? Wq : (z == 1) ? Wk : (z == 2) ? Wv : Wo;
  unsigned short* Wt = (z < 3) ? (Wt3 + (size_t)z * DM * DM) : Wto;
  const int tx = threadIdx.x & 31, ty = threadIdx.x >> 5;  // 32 x 8
  const int x0 = blockIdx.x * 32, y0 = blockIdx.y * 32;    // x0: n, y0: k
  #pragma unroll
  for (int i = 0; i < 4; ++i)
    tl[ty + i * 8][tx] = W[(size_t)(y0 + ty + i * 8) * DM + x0 + tx];
  __syncthreads();
  #pragma unroll
  for (int i = 0; i < 4; ++i)
    Wt[(size_t)(x0 + ty + i * 8) * DM + y0 + tx] = f2bf(tl[tx][ty + i * 8]);
}

// -------- V transpose: [B,H,S,DK] -> [B,H,DK,S], 64x64 bf16 tiles --------
__global__ __launch_bounds__(256)
void transpose_v(const unsigned short* __restrict__ V, unsigned short* __restrict__ Vt) {
  __shared__ unsigned short tl[64 * 64];
  const int t = threadIdx.x;
  const int s0 = blockIdx.x * 64, bh = blockIdx.y;
  const unsigned short* src = V + (size_t)bh * SQ * DK;
  unsigned short* dst = Vt + (size_t)bh * DK * SQ;
  #pragma unroll
  for (int i = 0; i < 2; ++i) {
    int g = t + i * 256, r = g >> 3, cg = g & 7;
    uint4 v = *(const uint4*)&src[(size_t)(s0 + r) * DK + cg * 8];
    *(uint4*)&tl[r * 64 + (((cg ^ fswz(r)) & 7) << 3)] = v;
  }
  __syncthreads();
  #pragma unroll
  for (int i = 0; i < 2; ++i) {
    int g = t + i * 256, d = g >> 3, cs = g & 7;
    uint4 o;
    unsigned short* op = (unsigned short*)&o;
    #pragma unroll
    for (int e = 0; e < 8; ++e)
      op[e] = tl[swz(cs * 8 + e, d)];
    *(uint4*)&dst[(size_t)d * SQ + s0 + cs * 8] = o;
  }
}

// -------- fused QKV GEMM: [4096,1024] x Wt3[3072,1024]^T, 2-phase dbuf --------
// Q output scaled 1/8 (softmax scale folded). Bias selected by block column.
__global__ __launch_bounds__(256)
void qkv_gemm(const unsigned short* __restrict__ A, const unsigned short* __restrict__ Wt3,
              const float* __restrict__ bq, const float* __restrict__ bk,
              const float* __restrict__ bv, unsigned short* __restrict__ qkv)
{
  constexpr int K = DM;
  __shared__ unsigned short As[2][128 * 64];
  __shared__ unsigned short Bs[2][128 * 64];
  const int t = threadIdx.x;
  const int w = t >> 6, ln = t & 63;
  const int wr = w >> 1, wc = w & 1;
  const int rb = blockIdx.y * 128, cb = blockIdx.x * 128;

  f32x4 acc[4][4] = {};

  auto stage = [&](int buf, int k0) {
    #pragma unroll
    for (int j = 0; j < 4; ++j) {
      const int rows8 = (w * 4 + j) * 8;
      const int r = rows8 + (ln >> 3);
      const int gc = (((ln & 7) ^ fswz(r)) & 7) * 8;
      __builtin_amdgcn_global_load_lds(
          (const __attribute__((address_space(1))) void*)&A[(size_t)(rb + r) * K + k0 + gc],
          (__attribute__((address_space(3))) void*)&As[buf][rows8 * 64], 16, 0, 0);
      __builtin_amdgcn_global_load_lds(
          (const __attribute__((address_space(1))) void*)&Wt3[(size_t)(cb + r) * K + k0 + gc],
          (__attribute__((address_space(3))) void*)&Bs[buf][rows8 * 64], 16, 0, 0);
    }
  };

  stage(0, 0);
  asm volatile("s_waitcnt vmcnt(0)" ::: "memory");
  __builtin_amdgcn_s_barrier();

  for (int it = 0; it < K / 64; ++it) {
    const int buf = it & 1;
    if (it < K / 64 - 1) stage(buf ^ 1, (it + 1) * 64);
    const int rsel = ln & 15;
    #pragma unroll
    for (int kk = 0; kk < 2; ++kk) {
      const int ko = kk * 32 + (ln >> 4) * 8;
      bf16x8 af[4], bfr[4];
      #pragma unroll
      for (int m = 0; m < 4; ++m)
        af[m] = *(const bf16x8*)&As[buf][swz(wr * 64 + m * 16 + rsel, ko)];
      #pragma unroll
      for (int n = 0; n < 4; ++n)
        bfr[n] = *(const bf16x8*)&Bs[buf][swz(wc * 64 + n * 16 + rsel, ko)];
      #pragma unroll
      for (int m = 0; m < 4; ++m)
        #pragma unroll
        for (int n = 0; n < 4; ++n)
          acc[m][n] = __builtin_amdgcn_mfma_f32_16x16x32_bf16(af[m], bfr[n], acc[m][n], 0, 0, 0);
    }
    asm volatile("s_waitcnt vmcnt(0)" ::: "memory");
    __builtin_amdgcn_s_barrier();
  }

  const int cl = ln & 15, rg = (ln >> 4) * 4;
  const int which = cb >> 10;                 // 0=Q 1=K 2=V (block-uniform)
  const float sc = (which == 0) ? 0.125f : 1.0f;
  const float* bp = (which == 0) ? bq : (which == 1) ? bk : bv;
  unsigned short* dst0 = qkv + (size_t)which * MR * DM;
  #pragma unroll
  for (int m = 0; m < 4; ++m) {
    #pragma unroll
    for (int i = 0; i < 4; ++i) {
      const int r = rb + wr * 64 + m * 16 + rg + i;
      const int b = r >> 11, s = r & 2047;
      #pragma unroll
      for (int n = 0; n < 4; ++n) {
        const int c = cb + wc * 64 + n * 16 + cl;
        const int cc = c & 1023, h = cc >> 6, d = c & 63;
        const float v = (acc[m][n][i] + bp[cc]) * sc;
        dst0[(((size_t)(b * NH + h)) * SQ + s) * DK + d] = f2bf(v);
      }
    }
  }
}

// -------- bf16 MFMA GEMM (final projection), 2-phase dbuf --------
__global__ __launch_bounds__(256)
void mfma_gemm_out(const unsigned short* __restrict__ A, const unsigned short* __restrict__ Bt,
                   const float* __restrict__ bias, float* __restrict__ outp)
{
  constexpr int K = DM, N = DM;
  __shared__ unsigned short As[2][128 * 64];
  __shared__ unsigned short Bs[2][128 * 64];
  const int t = threadIdx.x;
  const int w = t >> 6, ln = t & 63;
  const int wr = w >> 1, wc = w & 1;
  const int rb = blockIdx.y * 128, cb = blockIdx.x * 128;

  f32x4 acc[4][4] = {};

  auto stage = [&](int buf, int k0) {
    #pragma unroll
    for (int j = 0; j < 4; ++j) {
      const int rows8 = (w * 4 + j) * 8;
      const int r = rows8 + (ln >> 3);
      const int gc = (((ln & 7) ^ fswz(r)) & 7) * 8;
      __builtin_amdgcn_global_load_lds(
          (const __attribute__((address_space(1))) void*)&A[(size_t)(rb + r) * K + k0 + gc],
          (__attribute__((address_space(3))) void*)&As[buf][rows8 * 64], 16, 0, 0);
      __builtin_amdgcn_global_load_lds(
          (const __attribute__((address_space(1))) void*)&Bt[(size_t)(cb + r) * K + k0 + gc],
          (__attribute__((address_space(3))) void*)&Bs[buf][rows8 * 64], 16, 0, 0);
    }
  };

  stage(0, 0);
  asm volatile("s_waitcnt vmcnt(0)" ::: "memory");
  __builtin_amdgcn_s_barrier();

  for (int it = 0; it < K / 64; ++it) {
    const int buf = it & 1;
    if (it < K / 64 - 1) stage(buf ^ 1, (it + 1) * 64);
    const int rsel = ln & 15;
    #pragma unroll
    for (int kk = 0; kk < 2; ++kk) {
      const int ko = kk * 32 + (ln >> 4) * 8;
      bf16x8 af[4], bfr[4];
      #pragma unroll
      for (int m = 0; m < 4; ++m)
        af[m] = *(const bf16x8*)&As[buf][swz(wr * 64 + m * 16 + rsel, ko)];
      #pragma unroll
      for (int n = 0; n < 4; ++n)
        bfr[n] = *(const bf16x8*)&Bs[buf][swz(wc * 64 + n * 16 + rsel, ko)];
      #pragma unroll
      for (int m = 0; m < 4; ++m)
        #pragma unroll
        for (int n = 0; n < 4; ++n)
          acc[m][n] = __builtin_amdgcn_mfma_f32_16x16x32_bf16(af[m], bfr[n], acc[m][n], 0, 0, 0);
    }
    asm volatile("s_waitcnt vmcnt(0)" ::: "memory");
    __builtin_amdgcn_s_barrier();
  }

  const int cl = ln & 15, rg = (ln >> 4) * 4;
  #pragma unroll
  for (int m = 0; m < 4; ++m) {
    #pragma unroll
    for (int i = 0; i < 4; ++i) {
      const int r = rb + wr * 64 + m * 16 + rg + i;
      #pragma unroll
      for (int n = 0; n < 4; ++n) {
        const int c = cb + wc * 64 + n * 16 + cl;
        outp[(size_t)r * N + c] = acc[m][n][i] + bias[c];
      }
    }
  }
}

// -------- MFMA flash attention: 512 thr = 4 q-waves x 2 KV-parts, 32x32 --------
// Per wave: 32 q-rows (QBLK=128/block), kv half (1024) in 16 chunks of 64.
// 32x32 MFMA, swapped QK^T, in-register P (cvt_pk + permlane32_swap, r12-
// verified), in-place exp (r15), in-LDS partition combine (r14). 48KB LDS.
__global__ __launch_bounds__(512)
void attn_split(const unsigned short* __restrict__ Qp, const unsigned short* __restrict__ Kp,
                const unsigned short* __restrict__ VTp, unsigned short* __restrict__ ctx)
{
  __shared__ unsigned short lds[24576];   // 48KB: Q 16K | K 2x8K | Vt 2x8K
  const int t = threadIdx.x, w = t >> 6, ln = t & 63;
  const int lh = ln >> 5;
  const int part = w >> 2, qw = w & 3, tp = t & 255;
  const int bh = blockIdx.x, q0 = blockIdx.y * 128;
  const int b = bh >> 4, h = bh & 15;
  const unsigned short* Qb = Qp + (size_t)bh * SQ * DK;
  const unsigned short* Kb = Kp + (size_t)bh * SQ * DK;
  const unsigned short* Vb = VTp + (size_t)bh * DK * SQ;   // [DK][SQ]

  // ---- stage Q [128][64] swizzled at lds[0..8192), hoist this wave's frags ----
  #pragma unroll
  for (int i = 0; i < 2; ++i) {
    int g = t + i * 512, r = g >> 3, cg = g & 7;
    uint4 qv = *(const uint4*)&Qb[(size_t)(q0 + r) * DK + cg * 8];
    *(uint4*)&lds[r * 64 + (((cg ^ fswz(r)) & 7) << 3)] = qv;
  }
  __syncthreads();
  bf16x8 qf[4];
  #pragma unroll
  for (int s = 0; s < 4; ++s)
    qf[s] = *(const bf16x8*)&lds[swz(qw * 32 + (ln & 31), s * 16 + lh * 8)];

  unsigned short* Ks = lds + 8192 + part * 4096;    // [64][64] swizzled
  unsigned short* Vt = lds + 16384 + part * 4096;   // [64 d][64 kv] swizzled

  f32x16 o0 = {}, o1 = {};     // O[q(reg)][d = (ln&31)] and [d = 32+(ln&31)]
  float m = -1e30f, l = 0.f;   // per-lane state for q = ln&31 (scores pre-scaled)

  // preload chunk 0 (part-local: 256 threads, 512 granules each of K and V^T)
  const int kvb = part * (SQ / 2);
  uint4 kg[2], vg[2];
  #pragma unroll
  for (int j = 0; j < 2; ++j) {
    int g = tp + j * 256;
    kg[j] = *(const uint4*)&Kb[(size_t)(kvb + (g >> 3)) * DK + (g & 7) * 8];
    vg[j] = *(const uint4*)&Vb[(size_t)(g >> 3) * SQ + kvb + (g & 7) * 8];
  }

  for (int ck = 0; ck < 16; ++ck) {
    __syncthreads();  // previous chunk's Ks/Vt reads done (all waves)
    #pragma unroll
    for (int j = 0; j < 2; ++j) {
      int g = tp + j * 256, r = g >> 3, cg = g & 7;
      *(uint4*)&Ks[r * 64 + (((cg ^ fswz(r)) & 7) << 3)] = kg[j];
      *(uint4*)&Vt[r * 64 + (((cg ^ fswz(r)) & 7) << 3)] = vg[j];  // r=d, cg=kv-oct
    }
    __syncthreads();

    if (ck < 15) {  // prefetch next chunk; lands under compute
      const int base = kvb + (ck + 1) * 64;
      #pragma unroll
      for (int j = 0; j < 2; ++j) {
        int g = tp + j * 256;
        kg[j] = *(const uint4*)&Kb[(size_t)(base + (g >> 3)) * DK + (g & 7) * 8];
        vg[j] = *(const uint4*)&Vb[(size_t)(g >> 3) * SQ + base + (g & 7) * 8];
      }
    }

    // ---- QK^T: S^T[kv 64][q 32], two 32x32 kv-subtiles ----
    f32x16 s0 = {}, s1 = {};
    __builtin_amdgcn_s_setprio(1);
    #pragma unroll
    for (int s = 0; s < 4; ++s) {
      bf16x8 k0 = *(const bf16x8*)&Ks[swz((ln & 31), s * 16 + lh * 8)];
      bf16x8 k1 = *(const bf16x8*)&Ks[swz(32 + (ln & 31), s * 16 + lh * 8)];
      s0 = __builtin_amdgcn_mfma_f32_32x32x16_bf16(k0, qf[s], s0, 0, 0, 0);
      s1 = __builtin_amdgcn_mfma_f32_32x32x16_bf16(k1, qf[s], s1, 0, 0, 0);
    }
    __builtin_amdgcn_s_setprio(0);

    // ---- online softmax for q = ln&31 ----
    float mx0 = fmaxf(s0[0], s0[1]), mx1 = fmaxf(s0[2], s0[3]);
    #pragma unroll
    for (int j = 4; j < 16; j += 4) {
      mx0 = fmaxf(mx0, fmaxf(s0[j], s0[j + 1]));
      mx1 = fmaxf(mx1, fmaxf(s0[j + 2], s0[j + 3]));
    }
    #pragma unroll
    for (int j = 0; j < 16; j += 4) {
      mx0 = fmaxf(mx0, fmaxf(s1[j], s1[j + 1]));
      mx1 = fmaxf(mx1, fmaxf(s1[j + 2], s1[j + 3]));
    }
    float tm = fmaxf(mx0, mx1);
    tm = fmaxf(tm, __shfl_xor(tm, 32));

    if (__any((tm - m) > 8.f)) {  // defer-max (THR=8)
      const float mnew = fmaxf(m, tm);
      const float corr = __expf(m - mnew);
      float ci[16];
      #pragma unroll
      for (int j = 0; j < 16; ++j)
        ci[j] = __shfl(corr, (j & 3) + 8 * (j >> 2) + 4 * lh);
      #pragma unroll
      for (int j = 0; j < 16; ++j) { o0[j] *= ci[j]; o1[j] *= ci[j]; }
      l *= corr;
      m = mnew;
    }

    // exp in place (s0/s1 become P)
    #pragma unroll
    for (int j = 0; j < 16; ++j) {
      s0[j] = __expf(s0[j] - m);
      s1[j] = __expf(s1[j] - m);
    }
    float ps = 0.f;
    #pragma unroll
    for (int j = 0; j < 16; ++j) ps += s0[j] + s1[j];
    ps += __shfl_xor(ps, 32);
    l += ps;

    // ---- PV: A-frags from regs (cvt_pk + permlane32_swap), B from Vt ----
    __builtin_amdgcn_s_setprio(1);
    #pragma unroll
    for (int s = 0; s < 4; ++s) {
      unsigned w0, w1, w2, w3;
      if (s == 0) {
        asm("v_cvt_pk_bf16_f32 %0, %1, %2" : "=v"(w0) : "v"(s0[0]), "v"(s0[1]));
        asm("v_cvt_pk_bf16_f32 %0, %1, %2" : "=v"(w1) : "v"(s0[2]), "v"(s0[3]));
        asm("v_cvt_pk_bf16_f32 %0, %1, %2" : "=v"(w2) : "v"(s0[4]), "v"(s0[5]));
        asm("v_cvt_pk_bf16_f32 %0, %1, %2" : "=v"(w3) : "v"(s0[6]), "v"(s0[7]));
      } else if (s == 1) {
        asm("v_cvt_pk_bf16_f32 %0, %1, %2" : "=v"(w0) : "v"(s0[8]), "v"(s0[9]));
        asm("v_cvt_pk_bf16_f32 %0, %1, %2" : "=v"(w1) : "v"(s0[10]), "v"(s0[11]));
        asm("v_cvt_pk_bf16_f32 %0, %1, %2" : "=v"(w2) : "v"(s0[12]), "v"(s0[13]));
        asm("v_cvt_pk_bf16_f32 %0, %1, %2" : "=v"(w3) : "v"(s0[14]), "v"(s0[15]));
      } else if (s == 2) {
        asm("v_cvt_pk_bf16_f32 %0, %1, %2" : "=v"(w0) : "v"(s1[0]), "v"(s1[1]));
        asm("v_cvt_pk_bf16_f32 %0, %1, %2" : "=v"(w1) : "v"(s1[2]), "v"(s1[3]));
        asm("v_cvt_pk_bf16_f32 %0, %1, %2" : "=v"(w2) : "v"(s1[4]), "v"(s1[5]));
        asm("v_cvt_pk_bf16_f32 %0, %1, %2" : "=v"(w3) : "v"(s1[6]), "v"(s1[7]));
      } else {
        asm("v_cvt_pk_bf16_f32 %0, %1, %2" : "=v"(w0) : "v"(s1[8]), "v"(s1[9]));
        asm("v_cvt_pk_bf16_f32 %0, %1, %2" : "=v"(w1) : "v"(s1[10]), "v"(s1[11]));
        asm("v_cvt_pk_bf16_f32 %0, %1, %2" : "=v"(w2) : "v"(s1[12]), "v"(s1[13]));
        asm("v_cvt_pk_bf16_f32 %0, %1, %2" : "=v"(w3) : "v"(s1[14]), "v"(s1[15]));
      }
      asm("v_permlane32_swap_b32 %0, %1" : "+v"(w0), "+v"(w2));
      asm("v_permlane32_swap_b32 %0, %1" : "+v"(w1), "+v"(w3));
      union { unsigned u[4]; bf16x8 v; } pa;
      pa.u[0] = w0; pa.u[1] = w1; pa.u[2] = w2; pa.u[3] = w3;
      const int gx = s * 2 + lh;  // kv-granule within [0,8)
      bf16x8 v0 = *(const bf16x8*)&Vt[(ln & 31) * 64 + (((gx ^ fswz(ln & 31)) & 7) << 3)];
      bf16x8 v1 = *(const bf16x8*)&Vt[(32 + (ln & 31)) * 64 + (((gx ^ fswz(32 + (ln & 31))) & 7) << 3)];
      o0 = __builtin_amdgcn_mfma_f32_32x32x16_bf16(pa.v, v0, o0, 0, 0, 0);
      o1 = __builtin_amdgcn_mfma_f32_32x32x16_bf16(pa.v, v1, o1, 0, 0, 0);
    }
    __builtin_amdgcn_s_setprio(0);
  }

  // ---- in-LDS partition combine ----
  __syncthreads();  // all waves done with K/V LDS regions
  float* Obuf = (float*)&lds[8192];   // 4 qw x 2048 f32 = 32KB (K/V region)
  float* mlb  = (float*)lds;          // 4 qw x 128 f32 (Q region, dead)
  if (part == 1) {
    #pragma unroll
    for (int j = 0; j < 16; ++j) {
      Obuf[qw * 2048 + j * 64 + ln]        = o0[j];
      Obuf[qw * 2048 + (16 + j) * 64 + ln] = o1[j];
    }
    mlb[qw * 128 + ln * 2]     = m;
    mlb[qw * 128 + ln * 2 + 1] = l;
  }
  __syncthreads();
  if (part == 0) {
    const float m1 = mlb[qw * 128 + ln * 2];
    const float l1 = mlb[qw * 128 + ln * 2 + 1];
    const float M  = fmaxf(m, m1);
    const float e0 = __expf(m - M), e1 = __expf(m1 - M);
    const float rl = 1.0f / (l * e0 + l1 * e1);
    const float f0 = e0 * rl, f1 = e1 * rl;
    #pragma unroll
    for (int j = 0; j < 16; ++j) {
      const int crow = (j & 3) + 8 * (j >> 2) + 4 * lh;
      const float a0 = __shfl(f0, crow);
      const float a1 = __shfl(f1, crow);
      const float v0 = o0[j] * a0 + Obuf[qw * 2048 + j * 64 + ln] * a1;
      const float v1 = o1[j] * a0 + Obuf[qw * 2048 + (16 + j) * 64 + ln] * a1;
      const int srow = q0 + qw * 32 + crow;
      unsigned short* dst = ctx + ((size_t)(b * SQ + srow)) * DM + h * 64;
      dst[ln & 31]        = f2bf(v0);
      dst[32 + (ln & 31)] = f2bf(v1);
    }
  }
}

extern "C" void kernel_launch(void* const* d_in, const int* in_sizes, int n_in,
                              void* d_out, int out_size, void* d_ws, size_t ws_size,
                              hipStream_t stream) {
  const float* x  = (const float*)d_in[0];
  const float* Wq = (const float*)d_in[1];
  const float* bq = (const float*)d_in[2];
  const float* Wk = (const float*)d_in[3];
  const float* bk = (const float*)d_in[4];
  const float* Wv = (const float*)d_in[5];
  const float* bv = (const float*)d_in[6];
  const float* Wo = (const float*)d_in[7];
  const float* bo = (const float*)d_in[8];
  float* out = (float*)d_out;

  unsigned short* xb    = (unsigned short*)d_ws;             // [MR,DM] bf16, 8MB
  unsigned short* Wt3   = xb   + (size_t)MR * DM;            // [3072,1024] bf16, 6MB
  unsigned short* Wto   = Wt3  + (size_t)3 * DM * DM;        // [1024,1024] bf16, 2MB
  unsigned short* QKVb  = Wto  + (size_t)DM * DM;            // 3x [B,H,S,DK] bf16, 24MB
  unsigned short* Vtb   = QKVb + (size_t)3 * MR * DM;        // [B,H,DK,S] bf16, 8MB
  unsigned short* ctxb  = Vtb  + (size_t)MR * DM;            // [B,S,DM] bf16, 8MB
  // total ~56 MB

  cast_kernel<<<(MR * DM / 8 + 255) / 256, 256, 0, stream>>>(x, xb, MR * DM / 8);
  transpose_cast_all<<<dim3(DM / 32, DM / 32, 4), 256, 0, stream>>>(
      Wq, Wk, Wv, Wo, Wt3, Wto);

  qkv_gemm<<<dim3(3 * DM / 128, MR / 128), 256, 0, stream>>>(
      xb, Wt3, bq, bk, bv, QKVb);
  transpose_v<<<dim3(SQ / 64, BB * NH), 256, 0, stream>>>(
      QKVb + (size_t)2 * MR * DM, Vtb);

  attn_split<<<dim3(BB * NH, SQ / 128), 512, 0, stream>>>(
      QKVb, QKVb + (size_t)MR * DM, Vtb, ctxb);

  mfma_gemm_out<<<dim3(DM / 128, MR / 128), 256, 0, stream>>>(ctxb, Wto, bo, out);
}

// Round 18
// 145.745 us; speedup vs baseline: 1.2700x; 1.2700x over previous
//
#include <hip/hip_runtime.h>
#include <hip/hip_bf16.h>
#include <math.h>

constexpr int DM = 1024;    // d_model
constexpr int NH = 16;      // heads
constexpr int DK = 64;      // head dim
constexpr int SQ = 2048;    // seq len
constexpr int BB = 2;       // batch
constexpr int MR = BB * SQ; // 4096 rows

typedef short bf16x8 __attribute__((ext_vector_type(8)));
typedef float f32x4 __attribute__((ext_vector_type(4)));

__device__ inline unsigned short f2bf(float f) {
  unsigned u = __float_as_uint(f);
  unsigned r = (u + 0x7fffu + ((u >> 16) & 1u)) >> 16;  // RNE
  return (unsigned short)r;
}

// XOR swizzle for [R][64] bf16 LDS tiles. f(r) xors the 16B-granule index.
__device__ inline int fswz(int r) { return (r & 7) ^ ((r >> 3) & 7); }
__device__ inline int swz(int r, int c) {
  return r * 64 + ((((c >> 3) ^ fswz(r)) & 7) << 3) + (c & 7);
}

// -------- cast f32 -> bf16, 8 elems/thread --------
__global__ __launch_bounds__(256)
void cast_kernel(const float* __restrict__ in, unsigned short* __restrict__ out, int n8) {
  int i = blockIdx.x * 256 + threadIdx.x;
  if (i >= n8) return;
  float4 a = *(const float4*)&in[(size_t)i * 8];
  float4 b = *(const float4*)&in[(size_t)i * 8 + 4];
  ushort4 lo = {f2bf(a.x), f2bf(a.y), f2bf(a.z), f2bf(a.w)};
  ushort4 hi = {f2bf(b.x), f2bf(b.y), f2bf(b.z), f2bf(b.w)};
  *(ushort4*)&out[(size_t)i * 8] = lo;
  *(ushort4*)&out[(size_t)i * 8 + 4] = hi;
}

// -------- cast+transpose all 4 weights: z picks {Wq,Wk,Wv,Wo} --------
__global__ __launch_bounds__(256)
void transpose_cast_all(const float* __restrict__ Wq, const float* __restrict__ Wk,
                        const float* __restrict__ Wv, const float* __restrict__ Wo,
                        unsigned short* __restrict__ Wt3, unsigned short* __restrict__ Wto) {
  __shared__ float tl[32][33];
  const int z = blockIdx.z;
  const float* W = (z == 0) ? Wq : (z == 1) ? Wk : (z == 2) ? Wv : Wo;
  unsigned short* Wt = (z < 3) ? (Wt3 + (size_t)z * DM * DM) : Wto;
  const int tx = threadIdx.x & 31, ty = threadIdx.x >> 5;  // 32 x 8
  const int x0 = blockIdx.x * 32, y0 = blockIdx.y * 32;    // x0: n, y0: k
  #pragma unroll
  for (int i = 0; i < 4; ++i)
    tl[ty + i * 8][tx] = W[(size_t)(y0 + ty + i * 8) * DM + x0 + tx];
  __syncthreads();
  #pragma unroll
  for (int i = 0; i < 4; ++i)
    Wt[(size_t)(x0 + ty + i * 8) * DM + y0 + tx] = f2bf(tl[tx][ty + i * 8]);
}

// -------- fused QKV GEMM: [4096,1024] x Wt3[3072,1024]^T, 2-phase dbuf --------
// Q output scaled 1/8 (softmax scale folded). Bias selected by block column.
__global__ __launch_bounds__(256)
void qkv_gemm(const unsigned short* __restrict__ A, const unsigned short* __restrict__ Wt3,
              const float* __restrict__ bq, const float* __restrict__ bk,
              const float* __restrict__ bv, unsigned short* __restrict__ qkv)
{
  constexpr int K = DM;
  __shared__ unsigned short As[2][128 * 64];
  __shared__ unsigned short Bs[2][128 * 64];
  const int t = threadIdx.x;
  const int w = t >> 6, ln = t & 63;
  const int wr = w >> 1, wc = w & 1;
  const int rb = blockIdx.y * 128, cb = blockIdx.x * 128;

  f32x4 acc[4][4] = {};

  auto stage = [&](int buf, int k0) {
    #pragma unroll
    for (int j = 0; j < 4; ++j) {
      const int rows8 = (w * 4 + j) * 8;
      const int r = rows8 + (ln >> 3);
      const int gc = (((ln & 7) ^ fswz(r)) & 7) * 8;
      __builtin_amdgcn_global_load_lds(
          (const __attribute__((address_space(1))) void*)&A[(size_t)(rb + r) * K + k0 + gc],
          (__attribute__((address_space(3))) void*)&As[buf][rows8 * 64], 16, 0, 0);
      __builtin_amdgcn_global_load_lds(
          (const __attribute__((address_space(1))) void*)&Wt3[(size_t)(cb + r) * K + k0 + gc],
          (__attribute__((address_space(3))) void*)&Bs[buf][rows8 * 64], 16, 0, 0);
    }
  };

  stage(0, 0);
  asm volatile("s_waitcnt vmcnt(0)" ::: "memory");
  __builtin_amdgcn_s_barrier();

  for (int it = 0; it < K / 64; ++it) {
    const int buf = it & 1;
    if (it < K / 64 - 1) stage(buf ^ 1, (it + 1) * 64);
    const int rsel = ln & 15;
    #pragma unroll
    for (int kk = 0; kk < 2; ++kk) {
      const int ko = kk * 32 + (ln >> 4) * 8;
      bf16x8 af[4], bfr[4];
      #pragma unroll
      for (int m = 0; m < 4; ++m)
        af[m] = *(const bf16x8*)&As[buf][swz(wr * 64 + m * 16 + rsel, ko)];
      #pragma unroll
      for (int n = 0; n < 4; ++n)
        bfr[n] = *(const bf16x8*)&Bs[buf][swz(wc * 64 + n * 16 + rsel, ko)];
      #pragma unroll
      for (int m = 0; m < 4; ++m)
        #pragma unroll
        for (int n = 0; n < 4; ++n)
          acc[m][n] = __builtin_amdgcn_mfma_f32_16x16x32_bf16(af[m], bfr[n], acc[m][n], 0, 0, 0);
    }
    asm volatile("s_waitcnt vmcnt(0)" ::: "memory");
    __builtin_amdgcn_s_barrier();
  }

  const int cl = ln & 15, rg = (ln >> 4) * 4;
  const int which = cb >> 10;                 // 0=Q 1=K 2=V (block-uniform)
  const float sc = (which == 0) ? 0.125f : 1.0f;
  const float* bp = (which == 0) ? bq : (which == 1) ? bk : bv;
  unsigned short* dst0 = qkv + (size_t)which * MR * DM;
  #pragma unroll
  for (int m = 0; m < 4; ++m) {
    #pragma unroll
    for (int i = 0; i < 4; ++i) {
      const int r = rb + wr * 64 + m * 16 + rg + i;
      const int b = r >> 11, s = r & 2047;
      #pragma unroll
      for (int n = 0; n < 4; ++n) {
        const int c = cb + wc * 64 + n * 16 + cl;
        const int cc = c & 1023, h = cc >> 6, d = c & 63;
        const float v = (acc[m][n][i] + bp[cc]) * sc;
        dst0[(((size_t)(b * NH + h)) * SQ + s) * DK + d] = f2bf(v);
      }
    }
  }
}

// -------- bf16 MFMA GEMM (final projection), 2-phase dbuf --------
__global__ __launch_bounds__(256)
void mfma_gemm_out(const unsigned short* __restrict__ A, const unsigned short* __restrict__ Bt,
                   const float* __restrict__ bias, float* __restrict__ outp)
{
  constexpr int K = DM, N = DM;
  __shared__ unsigned short As[2][128 * 64];
  __shared__ unsigned short Bs[2][128 * 64];
  const int t = threadIdx.x;
  const int w = t >> 6, ln = t & 63;
  const int wr = w >> 1, wc = w & 1;
  const int rb = blockIdx.y * 128, cb = blockIdx.x * 128;

  f32x4 acc[4][4] = {};

  auto stage = [&](int buf, int k0) {
    #pragma unroll
    for (int j = 0; j < 4; ++j) {
      const int rows8 = (w * 4 + j) * 8;
      const int r = rows8 + (ln >> 3);
      const int gc = (((ln & 7) ^ fswz(r)) & 7) * 8;
      __builtin_amdgcn_global_load_lds(
          (const __attribute__((address_space(1))) void*)&A[(size_t)(rb + r) * K + k0 + gc],
          (__attribute__((address_space(3))) void*)&As[buf][rows8 * 64], 16, 0, 0);
      __builtin_amdgcn_global_load_lds(
          (const __attribute__((address_space(1))) void*)&Bt[(size_t)(cb + r) * K + k0 + gc],
          (__attribute__((address_space(3))) void*)&Bs[buf][rows8 * 64], 16, 0, 0);
    }
  };

  stage(0, 0);
  asm volatile("s_waitcnt vmcnt(0)" ::: "memory");
  __builtin_amdgcn_s_barrier();

  for (int it = 0; it < K / 64; ++it) {
    const int buf = it & 1;
    if (it < K / 64 - 1) stage(buf ^ 1, (it + 1) * 64);
    const int rsel = ln & 15;
    #pragma unroll
    for (int kk = 0; kk < 2; ++kk) {
      const int ko = kk * 32 + (ln >> 4) * 8;
      bf16x8 af[4], bfr[4];
      #pragma unroll
      for (int m = 0; m < 4; ++m)
        af[m] = *(const bf16x8*)&As[buf][swz(wr * 64 + m * 16 + rsel, ko)];
      #pragma unroll
      for (int n = 0; n < 4; ++n)
        bfr[n] = *(const bf16x8*)&Bs[buf][swz(wc * 64 + n * 16 + rsel, ko)];
      #pragma unroll
      for (int m = 0; m < 4; ++m)
        #pragma unroll
        for (int n = 0; n < 4; ++n)
          acc[m][n] = __builtin_amdgcn_mfma_f32_16x16x32_bf16(af[m], bfr[n], acc[m][n], 0, 0, 0);
    }
    asm volatile("s_waitcnt vmcnt(0)" ::: "memory");
    __builtin_amdgcn_s_barrier();
  }

  const int cl = ln & 15, rg = (ln >> 4) * 4;
  #pragma unroll
  for (int m = 0; m < 4; ++m) {
    #pragma unroll
    for (int i = 0; i < 4; ++i) {
      const int r = rb + wr * 64 + m * 16 + rg + i;
      #pragma unroll
      for (int n = 0; n < 4; ++n) {
        const int c = cb + wc * 64 + n * 16 + cl;
        outp[(size_t)r * N + c] = acc[m][n][i] + bias[c];
      }
    }
  }
}

// -------- MFMA flash attention: 8 waves, QBLK=128 (round-10 kernel, verbatim) --------
// Measured 78.4 us @ VGPR 56, occupancy 34.7%. Q pre-scaled 1/8 in projection.
// Defer-max (THR=8), cvt_pk P pack, tree max, in-kernel V transpose at stage.
__global__ __launch_bounds__(512, 4)
void attn_mfma(const unsigned short* __restrict__ Qp, const unsigned short* __restrict__ Kp,
               const unsigned short* __restrict__ Vp, unsigned short* __restrict__ ctx)
{
  __shared__ unsigned short Qs[128 * 64];     // 16KB
  __shared__ unsigned short Ks[64 * 64];      // 8KB
  __shared__ unsigned short Vt[64 * 64];      // 8KB  V^T: [d][kv]
  __shared__ unsigned short Pl[8 * 16 * 64];  // 16KB per-wave P: [q][kk]
  const int t = threadIdx.x, w = t >> 6, ln = t & 63;
  const int bh = blockIdx.y, q0 = blockIdx.x * 128;
  const unsigned short* Qb = Qp + (size_t)bh * SQ * DK;
  const unsigned short* Kb = Kp + (size_t)bh * SQ * DK;
  const unsigned short* Vb = Vp + (size_t)bh * SQ * DK;

  // stage Q tile: 128 rows x 64 bf16 = 1024 granules, 2/thread (512 threads)
  #pragma unroll
  for (int i = 0; i < 2; ++i) {
    int g = t + i * 512, r = g >> 3, cg = g & 7;
    uint4 qv = *(const uint4*)&Qb[(size_t)(q0 + r) * DK + cg * 8];
    *(uint4*)&Qs[r * 64 + (((cg ^ fswz(r)) & 7) << 3)] = qv;
  }
  __syncthreads();
  const int rsel = ln & 15, ko = (ln >> 4) * 8;
  bf16x8 qf[2];
  #pragma unroll
  for (int kw = 0; kw < 2; ++kw)
    qf[kw] = *(const bf16x8*)&Qs[swz(w * 16 + rsel, ko + 32 * kw)];

  f32x4 acc2[4] = {};          // O[q=(ln>>4)*4+i][d=16n+rsel]
  float m = -1e30f, l = 0.f;   // per-lane state for q-row = rsel (scores pre-scaled)

  // preload KV tile 0: 512 granules each, 1/thread
  const int r0 = t >> 3, cg0 = t & 7;
  uint4 kg = *(const uint4*)&Kb[(size_t)r0 * DK + cg0 * 8];
  uint4 vg = *(const uint4*)&Vb[(size_t)r0 * DK + cg0 * 8];

  for (int c0 = 0; c0 < SQ; c0 += 64) {
    __syncthreads();  // previous tile's Ks/Vt reads done
    *(uint4*)&Ks[r0 * 64 + (((cg0 ^ fswz(r0)) & 7) << 3)] = kg;
    {
      const unsigned short* vv = (const unsigned short*)&vg;
      const int d0 = cg0 * 8;
      #pragma unroll
      for (int e = 0; e < 8; ++e)
        Vt[swz(d0 + e, r0)] = vv[e];   // transpose write, <=2-way banks
    }
    __syncthreads();

    if (c0 + 64 < SQ) {  // prefetch next KV tile under compute
      kg = *(const uint4*)&Kb[(size_t)(c0 + 64 + r0) * DK + cg0 * 8];
      vg = *(const uint4*)&Vb[(size_t)(c0 + 64 + r0) * DK + cg0 * 8];
    }

    // QK^T (swapped): lane holds S[kv=fr*16+(ln>>4)*4+i][q=rsel], pre-scaled
    f32x4 s[4] = {};
    __builtin_amdgcn_s_setprio(1);
    #pragma unroll
    for (int kw = 0; kw < 2; ++kw)
      #pragma unroll
      for (int fr = 0; fr < 4; ++fr) {
        bf16x8 kf = *(const bf16x8*)&Ks[swz(fr * 16 + rsel, ko + 32 * kw)];
        s[fr] = __builtin_amdgcn_mfma_f32_16x16x32_bf16(kf, qf[kw], s[fr], 0, 0, 0);
      }
    __builtin_amdgcn_s_setprio(0);

    // row max, tree-structured, then cross-replica combine
    float t0 = fmaxf(fmaxf(s[0][0], s[0][1]), fmaxf(s[0][2], s[0][3]));
    float t1 = fmaxf(fmaxf(s[1][0], s[1][1]), fmaxf(s[1][2], s[1][3]));
    float t2 = fmaxf(fmaxf(s[2][0], s[2][1]), fmaxf(s[2][2], s[2][3]));
    float t3 = fmaxf(fmaxf(s[3][0], s[3][1]), fmaxf(s[3][2], s[3][3]));
    float tm = fmaxf(fmaxf(t0, t1), fmaxf(t2, t3));
    tm = fmaxf(tm, __shfl_xor(tm, 16));
    tm = fmaxf(tm, __shfl_xor(tm, 32));

    // defer-max: only rescale when some row's max grew by > 8 (P <= e^8)
    if (__any((tm - m) > 8.f)) {
      const float mnew = fmaxf(m, tm);
      const float corr = __expf(m - mnew);
      float ci[4];
      #pragma unroll
      for (int i = 0; i < 4; ++i) ci[i] = __shfl(corr, (ln >> 4) * 4 + i);
      #pragma unroll
      for (int n = 0; n < 4; ++n)
        #pragma unroll
        for (int i = 0; i < 4; ++i) acc2[n][i] *= ci[i];
      l *= corr;
      m = mnew;
    }

    float p[4][4];
    #pragma unroll
    for (int fr = 0; fr < 4; ++fr)
      #pragma unroll
      for (int i = 0; i < 4; ++i)
        p[fr][i] = __expf(s[fr][i] - m);
    float a0 = (p[0][0] + p[0][1]) + (p[0][2] + p[0][3]);
    float a1 = (p[1][0] + p[1][1]) + (p[1][2] + p[1][3]);
    float a2 = (p[2][0] + p[2][1]) + (p[2][2] + p[2][3]);
    float a3 = (p[3][0] + p[3][1]) + (p[3][2] + p[3][3]);
    float ps = (a0 + a1) + (a2 + a3);
    ps += __shfl_xor(ps, 16);
    ps += __shfl_xor(ps, 32);
    l += ps;

    // pack P (v_cvt_pk_bf16_f32) and write to this wave's LDS region
    #pragma unroll
    for (int fr = 0; fr < 4; ++fr) {
      unsigned r01, r23;
      asm("v_cvt_pk_bf16_f32 %0, %1, %2" : "=v"(r01) : "v"(p[fr][0]), "v"(p[fr][1]));
      asm("v_cvt_pk_bf16_f32 %0, %1, %2" : "=v"(r23) : "v"(p[fr][2]), "v"(p[fr][3]));
      uint2 pv = {r01, r23};
      const int kk0 = (ln >> 4) * 4 + fr * 16;
      *(uint2*)&Pl[w * 1024 + swz(rsel, kk0)] = pv;
    }

    // PV: A = P rows (wave-local region), B = Vt rows
    __builtin_amdgcn_s_setprio(1);
    #pragma unroll
    for (int kw = 0; kw < 2; ++kw) {
      bf16x8 pf = *(const bf16x8*)&Pl[w * 1024 + swz(rsel, ko + 32 * kw)];
      #pragma unroll
      for (int n = 0; n < 4; ++n) {
        bf16x8 vf = *(const bf16x8*)&Vt[swz(n * 16 + rsel, ko + 32 * kw)];
        acc2[n] = __builtin_amdgcn_mfma_f32_16x16x32_bf16(pf, vf, acc2[n], 0, 0, 0);
      }
    }
    __builtin_amdgcn_s_setprio(0);
  }

  // epilogue: divide by l (per output row) and store bf16 ctx [B][S][DM]
  const float rl = 1.0f / l;
  float ri[4];
  #pragma unroll
  for (int i = 0; i < 4; ++i) ri[i] = __shfl(rl, (ln >> 4) * 4 + i);
  const int b = bh >> 4, h = bh & 15;
  #pragma unroll
  for (int n = 0; n < 4; ++n)
    #pragma unroll
    for (int i = 0; i < 4; ++i) {
      const int srow = q0 + w * 16 + (ln >> 4) * 4 + i;
      ctx[((size_t)(b * SQ + srow)) * DM + h * 64 + n * 16 + rsel] =
          f2bf(acc2[n][i] * ri[i]);
    }
}

extern "C" void kernel_launch(void* const* d_in, const int* in_sizes, int n_in,
                              void* d_out, int out_size, void* d_ws, size_t ws_size,
                              hipStream_t stream) {
  const float* x  = (const float*)d_in[0];
  const float* Wq = (const float*)d_in[1];
  const float* bq = (const float*)d_in[2];
  const float* Wk = (const float*)d_in[3];
  const float* bk = (const float*)d_in[4];
  const float* Wv = (const float*)d_in[5];
  const float* bv = (const float*)d_in[6];
  const float* Wo = (const float*)d_in[7];
  const float* bo = (const float*)d_in[8];
  float* out = (float*)d_out;

  unsigned short* xb    = (unsigned short*)d_ws;             // [MR,DM] bf16, 8MB
  unsigned short* Wt3   = xb   + (size_t)MR * DM;            // [3072,1024] bf16, 6MB
  unsigned short* Wto   = Wt3  + (size_t)3 * DM * DM;        // [1024,1024] bf16, 2MB
  unsigned short* QKVb  = Wto  + (size_t)DM * DM;            // 3x [B,H,S,DK] bf16, 24MB
  unsigned short* ctxb  = QKVb + (size_t)3 * MR * DM;        // [B,S,DM] bf16, 8MB
  // total ~48 MB

  cast_kernel<<<(MR * DM / 8 + 255) / 256, 256, 0, stream>>>(x, xb, MR * DM / 8);
  transpose_cast_all<<<dim3(DM / 32, DM / 32, 4), 256, 0, stream>>>(
      Wq, Wk, Wv, Wo, Wt3, Wto);

  qkv_gemm<<<dim3(3 * DM / 128, MR / 128), 256, 0, stream>>>(
      xb, Wt3, bq, bk, bv, QKVb);

  attn_mfma<<<dim3(SQ / 128, BB * NH), 512, 0, stream>>>(
      QKVb, QKVb + (size_t)MR * DM, QKVb + (size_t)2 * MR * DM, ctxb);

  mfma_gemm_out<<<dim3(DM / 128, MR / 128), 256, 0, stream>>>(ctxb, Wto, bo, out);
}

// Round 19
// 145.709 us; speedup vs baseline: 1.2703x; 1.0002x over previous
//
#include <hip/hip_runtime.h>
#include <hip/hip_bf16.h>
#include <math.h>

constexpr int DM = 1024;    // d_model
constexpr int NH = 16;      // heads
constexpr int DK = 64;      // head dim
constexpr int SQ = 2048;    // seq len
constexpr int BB = 2;       // batch
constexpr int MR = BB * SQ; // 4096 rows

typedef short bf16x8 __attribute__((ext_vector_type(8)));
typedef float f32x4 __attribute__((ext_vector_type(4)));

__device__ inline unsigned short f2bf(float f) {
  unsigned u = __float_as_uint(f);
  unsigned r = (u + 0x7fffu + ((u >> 16) & 1u)) >> 16;  // RNE
  return (unsigned short)r;
}

// XOR swizzle for [R][64] bf16 LDS tiles. f(r) xors the 16B-granule index.
__device__ inline int fswz(int r) { return (r & 7) ^ ((r >> 3) & 7); }
__device__ inline int swz(int r, int c) {
  return r * 64 + ((((c >> 3) ^ fswz(r)) & 7) << 3) + (c & 7);
}

// -------- cast f32 -> bf16, 8 elems/thread --------
__global__ __launch_bounds__(256)
void cast_kernel(const float* __restrict__ in, unsigned short* __restrict__ out, int n8) {
  int i = blockIdx.x * 256 + threadIdx.x;
  if (i >= n8) return;
  float4 a = *(const float4*)&in[(size_t)i * 8];
  float4 b = *(const float4*)&in[(size_t)i * 8 + 4];
  ushort4 lo = {f2bf(a.x), f2bf(a.y), f2bf(a.z), f2bf(a.w)};
  ushort4 hi = {f2bf(b.x), f2bf(b.y), f2bf(b.z), f2bf(b.w)};
  *(ushort4*)&out[(size_t)i * 8] = lo;
  *(ushort4*)&out[(size_t)i * 8 + 4] = hi;
}

// -------- cast+transpose all 4 weights: z picks {Wq,Wk,Wv,Wo} --------
__global__ __launch_bounds__(256)
void transpose_cast_all(const float* __restrict__ Wq, const float* __restrict__ Wk,
                        const float* __restrict__ Wv, const float* __restrict__ Wo,
                        unsigned short* __restrict__ Wt3, unsigned short* __restrict__ Wto) {
  __shared__ float tl[32][33];
  const int z = blockIdx.z;
  const float* W = (z == 0) ? Wq : (z == 1) ? Wk : (z == 2) ? Wv : Wo;
  unsigned short* Wt = (z < 3) ? (Wt3 + (size_t)z * DM * DM) : Wto;
  const int tx = threadIdx.x & 31, ty = threadIdx.x >> 5;  // 32 x 8
  const int x0 = blockIdx.x * 32, y0 = blockIdx.y * 32;    // x0: n, y0: k
  #pragma unroll
  for (int i = 0; i < 4; ++i)
    tl[ty + i * 8][tx] = W[(size_t)(y0 + ty + i * 8) * DM + x0 + tx];
  __syncthreads();
  #pragma unroll
  for (int i = 0; i < 4; ++i)
    Wt[(size_t)(x0 + ty + i * 8) * DM + y0 + tx] = f2bf(tl[tx][ty + i * 8]);
}

// -------- V transpose: [B,H,S,DK] -> [B,H,DK,S], 64x64 bf16 tiles --------
__global__ __launch_bounds__(256)
void transpose_v(const unsigned short* __restrict__ V, unsigned short* __restrict__ Vt) {
  __shared__ unsigned short tl[64 * 64];
  const int t = threadIdx.x;
  const int s0 = blockIdx.x * 64, bh = blockIdx.y;
  const unsigned short* src = V + (size_t)bh * SQ * DK;
  unsigned short* dst = Vt + (size_t)bh * DK * SQ;
  #pragma unroll
  for (int i = 0; i < 2; ++i) {
    int g = t + i * 256, r = g >> 3, cg = g & 7;
    uint4 v = *(const uint4*)&src[(size_t)(s0 + r) * DK + cg * 8];
    *(uint4*)&tl[r * 64 + (((cg ^ fswz(r)) & 7) << 3)] = v;
  }
  __syncthreads();
  #pragma unroll
  for (int i = 0; i < 2; ++i) {
    int g = t + i * 256, d = g >> 3, cs = g & 7;
    uint4 o;
    unsigned short* op = (unsigned short*)&o;
    #pragma unroll
    for (int e = 0; e < 8; ++e)
      op[e] = tl[swz(cs * 8 + e, d)];
    *(uint4*)&dst[(size_t)d * SQ + s0 + cs * 8] = o;
  }
}

// -------- fused QKV GEMM: [4096,1024] x Wt3[3072,1024]^T, 2-phase dbuf --------
// Q output scaled 1/8 (softmax scale folded). Bias selected by block column.
__global__ __launch_bounds__(256)
void qkv_gemm(const unsigned short* __restrict__ A, const unsigned short* __restrict__ Wt3,
              const float* __restrict__ bq, const float* __restrict__ bk,
              const float* __restrict__ bv, unsigned short* __restrict__ qkv)
{
  constexpr int K = DM;
  __shared__ unsigned short As[2][128 * 64];
  __shared__ unsigned short Bs[2][128 * 64];
  const int t = threadIdx.x;
  const int w = t >> 6, ln = t & 63;
  const int wr = w >> 1, wc = w & 1;
  const int rb = blockIdx.y * 128, cb = blockIdx.x * 128;

  f32x4 acc[4][4] = {};

  auto stage = [&](int buf, int k0) {
    #pragma unroll
    for (int j = 0; j < 4; ++j) {
      const int rows8 = (w * 4 + j) * 8;
      const int r = rows8 + (ln >> 3);
      const int gc = (((ln & 7) ^ fswz(r)) & 7) * 8;
      __builtin_amdgcn_global_load_lds(
          (const __attribute__((address_space(1))) void*)&A[(size_t)(rb + r) * K + k0 + gc],
          (__attribute__((address_space(3))) void*)&As[buf][rows8 * 64], 16, 0, 0);
      __builtin_amdgcn_global_load_lds(
          (const __attribute__((address_space(1))) void*)&Wt3[(size_t)(cb + r) * K + k0 + gc],
          (__attribute__((address_space(3))) void*)&Bs[buf][rows8 * 64], 16, 0, 0);
    }
  };

  stage(0, 0);
  asm volatile("s_waitcnt vmcnt(0)" ::: "memory");
  __builtin_amdgcn_s_barrier();

  for (int it = 0; it < K / 64; ++it) {
    const int buf = it & 1;
    if (it < K / 64 - 1) stage(buf ^ 1, (it + 1) * 64);
    const int rsel = ln & 15;
    #pragma unroll
    for (int kk = 0; kk < 2; ++kk) {
      const int ko = kk * 32 + (ln >> 4) * 8;
      bf16x8 af[4], bfr[4];
      #pragma unroll
      for (int m = 0; m < 4; ++m)
        af[m] = *(const bf16x8*)&As[buf][swz(wr * 64 + m * 16 + rsel, ko)];
      #pragma unroll
      for (int n = 0; n < 4; ++n)
        bfr[n] = *(const bf16x8*)&Bs[buf][swz(wc * 64 + n * 16 + rsel, ko)];
      #pragma unroll
      for (int m = 0; m < 4; ++m)
        #pragma unroll
        for (int n = 0; n < 4; ++n)
          acc[m][n] = __builtin_amdgcn_mfma_f32_16x16x32_bf16(af[m], bfr[n], acc[m][n], 0, 0, 0);
    }
    asm volatile("s_waitcnt vmcnt(0)" ::: "memory");
    __builtin_amdgcn_s_barrier();
  }

  const int cl = ln & 15, rg = (ln >> 4) * 4;
  const int which = cb >> 10;                 // 0=Q 1=K 2=V (block-uniform)
  const float sc = (which == 0) ? 0.125f : 1.0f;
  const float* bp = (which == 0) ? bq : (which == 1) ? bk : bv;
  unsigned short* dst0 = qkv + (size_t)which * MR * DM;
  #pragma unroll
  for (int m = 0; m < 4; ++m) {
    #pragma unroll
    for (int i = 0; i < 4; ++i) {
      const int r = rb + wr * 64 + m * 16 + rg + i;
      const int b = r >> 11, s = r & 2047;
      #pragma unroll
      for (int n = 0; n < 4; ++n) {
        const int c = cb + wc * 64 + n * 16 + cl;
        const int cc = c & 1023, h = cc >> 6, d = c & 63;
        const float v = (acc[m][n][i] + bp[cc]) * sc;
        dst0[(((size_t)(b * NH + h)) * SQ + s) * DK + d] = f2bf(v);
      }
    }
  }
}

// -------- bf16 MFMA GEMM (final projection), 2-phase dbuf --------
__global__ __launch_bounds__(256)
void mfma_gemm_out(const unsigned short* __restrict__ A, const unsigned short* __restrict__ Bt,
                   const float* __restrict__ bias, float* __restrict__ outp)
{
  constexpr int K = DM, N = DM;
  __shared__ unsigned short As[2][128 * 64];
  __shared__ unsigned short Bs[2][128 * 64];
  const int t = threadIdx.x;
  const int w = t >> 6, ln = t & 63;
  const int wr = w >> 1, wc = w & 1;
  const int rb = blockIdx.y * 128, cb = blockIdx.x * 128;

  f32x4 acc[4][4] = {};

  auto stage = [&](int buf, int k0) {
    #pragma unroll
    for (int j = 0; j < 4; ++j) {
      const int rows8 = (w * 4 + j) * 8;
      const int r = rows8 + (ln >> 3);
      const int gc = (((ln & 7) ^ fswz(r)) & 7) * 8;
      __builtin_amdgcn_global_load_lds(
          (const __attribute__((address_space(1))) void*)&A[(size_t)(rb + r) * K + k0 + gc],
          (__attribute__((address_space(3))) void*)&As[buf][rows8 * 64], 16, 0, 0);
      __builtin_amdgcn_global_load_lds(
          (const __attribute__((address_space(1))) void*)&Bt[(size_t)(cb + r) * K + k0 + gc],
          (__attribute__((address_space(3))) void*)&Bs[buf][rows8 * 64], 16, 0, 0);
    }
  };

  stage(0, 0);
  asm volatile("s_waitcnt vmcnt(0)" ::: "memory");
  __builtin_amdgcn_s_barrier();

  for (int it = 0; it < K / 64; ++it) {
    const int buf = it & 1;
    if (it < K / 64 - 1) stage(buf ^ 1, (it + 1) * 64);
    const int rsel = ln & 15;
    #pragma unroll
    for (int kk = 0; kk < 2; ++kk) {
      const int ko = kk * 32 + (ln >> 4) * 8;
      bf16x8 af[4], bfr[4];
      #pragma unroll
      for (int m = 0; m < 4; ++m)
        af[m] = *(const bf16x8*)&As[buf][swz(wr * 64 + m * 16 + rsel, ko)];
      #pragma unroll
      for (int n = 0; n < 4; ++n)
        bfr[n] = *(const bf16x8*)&Bs[buf][swz(wc * 64 + n * 16 + rsel, ko)];
      #pragma unroll
      for (int m = 0; m < 4; ++m)
        #pragma unroll
        for (int n = 0; n < 4; ++n)
          acc[m][n] = __builtin_amdgcn_mfma_f32_16x16x32_bf16(af[m], bfr[n], acc[m][n], 0, 0, 0);
    }
    asm volatile("s_waitcnt vmcnt(0)" ::: "memory");
    __builtin_amdgcn_s_barrier();
  }

  const int cl = ln & 15, rg = (ln >> 4) * 4;
  #pragma unroll
  for (int m = 0; m < 4; ++m) {
    #pragma unroll
    for (int i = 0; i < 4; ++i) {
      const int r = rb + wr * 64 + m * 16 + rg + i;
      #pragma unroll
      for (int n = 0; n < 4; ++n) {
        const int c = cb + wc * 64 + n * 16 + cl;
        outp[(size_t)r * N + c] = acc[m][n][i] + bias[c];
      }
    }
  }
}

// -------- MFMA flash attention: 8 waves, QBLK=128 (round-10 structure) --------
// Identical to round-18 except the V path: V arrives pre-transposed [B,H,DK,S]
// and each thread stages one uint4 (granule [d][oct]) producing the byte-
// identical swizzled Vt layout the scalar transpose used; reads unchanged.
__global__ __launch_bounds__(512, 4)
void attn_mfma(const unsigned short* __restrict__ Qp, const unsigned short* __restrict__ Kp,
               const unsigned short* __restrict__ VTp, unsigned short* __restrict__ ctx)
{
  __shared__ unsigned short Qs[128 * 64];     // 16KB
  __shared__ unsigned short Ks[64 * 64];      // 8KB
  __shared__ unsigned short Vt[64 * 64];      // 8KB  V^T: [d][kv]
  __shared__ unsigned short Pl[8 * 16 * 64];  // 16KB per-wave P: [q][kk]
  const int t = threadIdx.x, w = t >> 6, ln = t & 63;
  const int bh = blockIdx.y, q0 = blockIdx.x * 128;
  const unsigned short* Qb = Qp + (size_t)bh * SQ * DK;
  const unsigned short* Kb = Kp + (size_t)bh * SQ * DK;
  const unsigned short* Vb = VTp + (size_t)bh * DK * SQ;   // [DK][SQ]

  // stage Q tile: 128 rows x 64 bf16 = 1024 granules, 2/thread (512 threads)
  #pragma unroll
  for (int i = 0; i < 2; ++i) {
    int g = t + i * 512, r = g >> 3, cg = g & 7;
    uint4 qv = *(const uint4*)&Qb[(size_t)(q0 + r) * DK + cg * 8];
    *(uint4*)&Qs[r * 64 + (((cg ^ fswz(r)) & 7) << 3)] = qv;
  }
  __syncthreads();
  const int rsel = ln & 15, ko = (ln >> 4) * 8;
  bf16x8 qf[2];
  #pragma unroll
  for (int kw = 0; kw < 2; ++kw)
    qf[kw] = *(const bf16x8*)&Qs[swz(w * 16 + rsel, ko + 32 * kw)];

  f32x4 acc2[4] = {};          // O[q=(ln>>4)*4+i][d=16n+rsel]
  float m = -1e30f, l = 0.f;   // per-lane state for q-row = rsel (scores pre-scaled)

  // preload KV tile 0: K rows (kv), V^T rows (d); 1 granule/thread each
  const int r0 = t >> 3, cg0 = t & 7;   // K: row r0, octet cg0; V^T: d=r0, kv-oct cg0
  uint4 kg = *(const uint4*)&Kb[(size_t)r0 * DK + cg0 * 8];
  uint4 vg = *(const uint4*)&Vb[(size_t)r0 * SQ + cg0 * 8];

  for (int c0 = 0; c0 < SQ; c0 += 64) {
    __syncthreads();  // previous tile's Ks/Vt reads done
    *(uint4*)&Ks[r0 * 64 + (((cg0 ^ fswz(r0)) & 7) << 3)] = kg;
    *(uint4*)&Vt[r0 * 64 + (((cg0 ^ fswz(r0)) & 7) << 3)] = vg;  // same layout as before
    __syncthreads();

    if (c0 + 64 < SQ) {  // prefetch next KV tile under compute
      kg = *(const uint4*)&Kb[(size_t)(c0 + 64 + r0) * DK + cg0 * 8];
      vg = *(const uint4*)&Vb[(size_t)r0 * SQ + c0 + 64 + cg0 * 8];
    }

    // QK^T (swapped): lane holds S[kv=fr*16+(ln>>4)*4+i][q=rsel], pre-scaled
    f32x4 s[4] = {};
    __builtin_amdgcn_s_setprio(1);
    #pragma unroll
    for (int kw = 0; kw < 2; ++kw)
      #pragma unroll
      for (int fr = 0; fr < 4; ++fr) {
        bf16x8 kf = *(const bf16x8*)&Ks[swz(fr * 16 + rsel, ko + 32 * kw)];
        s[fr] = __builtin_amdgcn_mfma_f32_16x16x32_bf16(kf, qf[kw], s[fr], 0, 0, 0);
      }
    __builtin_amdgcn_s_setprio(0);

    // row max, tree-structured, then cross-replica combine
    float t0 = fmaxf(fmaxf(s[0][0], s[0][1]), fmaxf(s[0][2], s[0][3]));
    float t1 = fmaxf(fmaxf(s[1][0], s[1][1]), fmaxf(s[1][2], s[1][3]));
    float t2 = fmaxf(fmaxf(s[2][0], s[2][1]), fmaxf(s[2][2], s[2][3]));
    float t3 = fmaxf(fmaxf(s[3][0], s[3][1]), fmaxf(s[3][2], s[3][3]));
    float tm = fmaxf(fmaxf(t0, t1), fmaxf(t2, t3));
    tm = fmaxf(tm, __shfl_xor(tm, 16));
    tm = fmaxf(tm, __shfl_xor(tm, 32));

    // defer-max: only rescale when some row's max grew by > 8 (P <= e^8)
    if (__any((tm - m) > 8.f)) {
      const float mnew = fmaxf(m, tm);
      const float corr = __expf(m - mnew);
      float ci[4];
      #pragma unroll
      for (int i = 0; i < 4; ++i) ci[i] = __shfl(corr, (ln >> 4) * 4 + i);
      #pragma unroll
      for (int n = 0; n < 4; ++n)
        #pragma unroll
        for (int i = 0; i < 4; ++i) acc2[n][i] *= ci[i];
      l *= corr;
      m = mnew;
    }

    float p[4][4];
    #pragma unroll
    for (int fr = 0; fr < 4; ++fr)
      #pragma unroll
      for (int i = 0; i < 4; ++i)
        p[fr][i] = __expf(s[fr][i] - m);
    float a0 = (p[0][0] + p[0][1]) + (p[0][2] + p[0][3]);
    float a1 = (p[1][0] + p[1][1]) + (p[1][2] + p[1][3]);
    float a2 = (p[2][0] + p[2][1]) + (p[2][2] + p[2][3]);
    float a3 = (p[3][0] + p[3][1]) + (p[3][2] + p[3][3]);
    float ps = (a0 + a1) + (a2 + a3);
    ps += __shfl_xor(ps, 16);
    ps += __shfl_xor(ps, 32);
    l += ps;

    // pack P (v_cvt_pk_bf16_f32) and write to this wave's LDS region
    #pragma unroll
    for (int fr = 0; fr < 4; ++fr) {
      unsigned r01, r23;
      asm("v_cvt_pk_bf16_f32 %0, %1, %2" : "=v"(r01) : "v"(p[fr][0]), "v"(p[fr][1]));
      asm("v_cvt_pk_bf16_f32 %0, %1, %2" : "=v"(r23) : "v"(p[fr][2]), "v"(p[fr][3]));
      uint2 pv = {r01, r23};
      const int kk0 = (ln >> 4) * 4 + fr * 16;
      *(uint2*)&Pl[w * 1024 + swz(rsel, kk0)] = pv;
    }

    // PV: A = P rows (wave-local region), B = Vt rows
    __builtin_amdgcn_s_setprio(1);
    #pragma unroll
    for (int kw = 0; kw < 2; ++kw) {
      bf16x8 pf = *(const bf16x8*)&Pl[w * 1024 + swz(rsel, ko + 32 * kw)];
      #pragma unroll
      for (int n = 0; n < 4; ++n) {
        bf16x8 vf = *(const bf16x8*)&Vt[swz(n * 16 + rsel, ko + 32 * kw)];
        acc2[n] = __builtin_amdgcn_mfma_f32_16x16x32_bf16(pf, vf, acc2[n], 0, 0, 0);
      }
    }
    __builtin_amdgcn_s_setprio(0);
  }

  // epilogue: divide by l (per output row) and store bf16 ctx [B][S][DM]
  const float rl = 1.0f / l;
  float ri[4];
  #pragma unroll
  for (int i = 0; i < 4; ++i) ri[i] = __shfl(rl, (ln >> 4) * 4 + i);
  const int b = bh >> 4, h = bh & 15;
  #pragma unroll
  for (int n = 0; n < 4; ++n)
    #pragma unroll
    for (int i = 0; i < 4; ++i) {
      const int srow = q0 + w * 16 + (ln >> 4) * 4 + i;
      ctx[((size_t)(b * SQ + srow)) * DM + h * 64 + n * 16 + rsel] =
          f2bf(acc2[n][i] * ri[i]);
    }
}

extern "C" void kernel_launch(void* const* d_in, const int* in_sizes, int n_in,
                              void* d_out, int out_size, void* d_ws, size_t ws_size,
                              hipStream_t stream) {
  const float* x  = (const float*)d_in[0];
  const float* Wq = (const float*)d_in[1];
  const float* bq = (const float*)d_in[2];
  const float* Wk = (const float*)d_in[3];
  const float* bk = (const float*)d_in[4];
  const float* Wv = (const float*)d_in[5];
  const float* bv = (const float*)d_in[6];
  const float* Wo = (const float*)d_in[7];
  const float* bo = (const float*)d_in[8];
  float* out = (float*)d_out;

  unsigned short* xb    = (unsigned short*)d_ws;             // [MR,DM] bf16, 8MB
  unsigned short* Wt3   = xb   + (size_t)MR * DM;            // [3072,1024] bf16, 6MB
  unsigned short* Wto   = Wt3  + (size_t)3 * DM * DM;        // [1024,1024] bf16, 2MB
  unsigned short* QKVb  = Wto  + (size_t)DM * DM;            // 3x [B,H,S,DK] bf16, 24MB
  unsigned short* Vtb   = QKVb + (size_t)3 * MR * DM;        // [B,H,DK,S] bf16, 8MB
  unsigned short* ctxb  = Vtb  + (size_t)MR * DM;            // [B,S,DM] bf16, 8MB
  // total ~56 MB

  cast_kernel<<<(MR * DM / 8 + 255) / 256, 256, 0, stream>>>(x, xb, MR * DM / 8);
  transpose_cast_all<<<dim3(DM / 32, DM / 32, 4), 256, 0, stream>>>(
      Wq, Wk, Wv, Wo, Wt3, Wto);

  qkv_gemm<<<dim3(3 * DM / 128, MR / 128), 256, 0, stream>>>(
      xb, Wt3, bq, bk, bv, QKVb);
  transpose_v<<<dim3(SQ / 64, BB * NH), 256, 0, stream>>>(
      QKVb + (size_t)2 * MR * DM, Vtb);

  attn_mfma<<<dim3(SQ / 128, BB * NH), 512, 0, stream>>>(
      QKVb, QKVb + (size_t)MR * DM, Vtb, ctxb);

  mfma_gemm_out<<<dim3(DM / 128, MR / 128), 256, 0, stream>>>(ctxb, Wto, bo, out);
}